// Round 1
// 716.037 us; speedup vs baseline: 1.0430x; 1.0430x over previous
//
#include <hip/hip_runtime.h>
#include <hip/hip_bf16.h>
#include <stdint.h>

#define NN 50000
#define EE 800000
#define DD 256
#define LL 3
#define NBLK 49      // ceil(NN/1024)
#define NPAD 50176   // 196*256

using floatx4 = __attribute__((ext_vector_type(4))) float;
using shortx8 = __attribute__((ext_vector_type(8))) short;

union U8 { shortx8 v; uint32_t u[4]; };

typedef __attribute__((address_space(1))) const unsigned int gu32;
typedef __attribute__((address_space(3))) unsigned int lu32;
__device__ __forceinline__ void async_copy16(const void* g, void* l) {
    __builtin_amdgcn_global_load_lds((gu32*)g, (lu32*)l, 16, 0, 0);
}

__device__ __forceinline__ uint16_t f2bf(float f) {
    __hip_bfloat16 h = __float2bfloat16(f);
    return *reinterpret_cast<uint16_t*>(&h);
}
__device__ __forceinline__ float bf2f(uint32_t u) {
    union { uint32_t u32; float f; } cv; cv.u32 = (u & 0xffffu) << 16; return cv.f;
}

// ---------------- CSR build ----------------
__global__ void k_count(const int* __restrict__ tgt, int* __restrict__ deg) {
    int e = blockIdx.x * 256 + threadIdx.x;
    if (e < EE) atomicAdd(&deg[tgt[e]], 1);
}

__global__ void k_scan1(const int* __restrict__ deg, int* __restrict__ row_start,
                        int* __restrict__ bsum) {
    __shared__ int wsum[16];
    int t = threadIdx.x, w = t >> 6, lane = t & 63;
    int i = blockIdx.x * 1024 + t;
    int v = (i < NN) ? deg[i] : 0;
    int s = v;
#pragma unroll
    for (int off = 1; off < 64; off <<= 1) {
        int u = __shfl_up(s, off);
        if (lane >= off) s += u;
    }
    if (lane == 63) wsum[w] = s;
    __syncthreads();
    if (t < 16) {
        int ws = wsum[t];
#pragma unroll
        for (int off = 1; off < 16; off <<= 1) {
            int u = __shfl_up(ws, off);
            if (t >= off) ws += u;
        }
        wsum[t] = ws;
    }
    __syncthreads();
    int off = (w > 0) ? wsum[w - 1] : 0;
    if (i < NN) row_start[i] = off + s - v;
    if (t == 1023) bsum[blockIdx.x] = off + s;
}

__global__ void k_scan2(int* __restrict__ bsum, int* __restrict__ row_start) {
    int t = threadIdx.x;
    int v = (t < NBLK) ? bsum[t] : 0;
    int s = v;
#pragma unroll
    for (int off = 1; off < 64; off <<= 1) {
        int u = __shfl_up(s, off);
        if (t >= off) s += u;
    }
    if (t < NBLK) bsum[t] = s - v;
    if (t == 0) row_start[NN] = EE;
}

__global__ void k_init2(const int* __restrict__ deg, const int* __restrict__ bsum,
                        int* __restrict__ row_start, int* __restrict__ cursor,
                        float* __restrict__ invd) {
    int i = blockIdx.x * 1024 + threadIdx.x;
    if (i < NN) {
        int r = row_start[i] + bsum[blockIdx.x];
        row_start[i] = r;
        cursor[i] = r;
        int d = deg[i];
        invd[i] = d > 0 ? 1.0f / (float)d : 0.0f;
    }
}

__global__ void k_scatter(const int* __restrict__ src, const int* __restrict__ tgt,
                          int* __restrict__ cursor, int* __restrict__ csr) {
    int e = blockIdx.x * 256 + threadIdx.x;
    if (e < EE) {
        int p = atomicAdd(&cursor[tgt[e]], 1);
        csr[p] = src[e];
    }
}

// ------- weight prep: fp32 W[i][k][n] -> transposed bf16 hi/lo Wt[i][n][k] -------
// Wr gets +I folded in: z = x@(Wr+I) reconstructs the residual x through the
// split path exactly (xh@I + xl@I, error ~2^-18), so k_finish never reloads xs2.
__global__ void k_wprep(const float* __restrict__ Wl, const float* __restrict__ Wr,
                        uint16_t* __restrict__ wtl_hi, uint16_t* __restrict__ wtl_lo,
                        uint16_t* __restrict__ wtr_hi, uint16_t* __restrict__ wtr_lo) {
    int d = blockIdx.x * 256 + threadIdx.x;
    int i = d >> 16, n = (d >> 8) & 255, k = d & 255;
    int s = (i << 16) | (k << 8) | n;
    float wl = Wl[s];
    float wr = Wr[s] + ((n == k) ? 1.0f : 0.0f);   // residual fold
    uint32_t ul = __float_as_uint(wl), ur = __float_as_uint(wr);
    wtl_hi[d] = (uint16_t)(ul >> 16);
    wtl_lo[d] = f2bf(wl - __uint_as_float(ul & 0xFFFF0000u));
    wtr_hi[d] = (uint16_t)(ur >> 16);
    wtr_lo[d] = f2bf(wr - __uint_as_float(ur & 0xFFFF0000u));
}

// ---- split x_init fp32 -> xs2 bf16 [NPAD][512]: cols 0-255 hi, 256-511 lo ----
__global__ void k_split0(const float* __restrict__ x, uint16_t* __restrict__ xs2) {
    int t = threadIdx.x;
    int row = blockIdx.x * 4 + (t >> 6);
    int col = (t & 63) * 4;
    uint32_t h01 = 0, h23 = 0, l01 = 0, l23 = 0;
    if (row < NN) {
        float4 v = *reinterpret_cast<const float4*>(x + (size_t)row * DD + col);
        uint32_t u0 = __float_as_uint(v.x), u1 = __float_as_uint(v.y);
        uint32_t u2 = __float_as_uint(v.z), u3 = __float_as_uint(v.w);
        h01 = (u0 >> 16) | (u1 & 0xFFFF0000u);
        h23 = (u2 >> 16) | (u3 & 0xFFFF0000u);
        l01 = (uint32_t)f2bf(v.x - __uint_as_float(u0 & 0xFFFF0000u))
            | ((uint32_t)f2bf(v.y - __uint_as_float(u1 & 0xFFFF0000u)) << 16);
        l23 = (uint32_t)f2bf(v.z - __uint_as_float(u2 & 0xFFFF0000u))
            | ((uint32_t)f2bf(v.w - __uint_as_float(u3 & 0xFFFF0000u)) << 16);
    }
    *reinterpret_cast<uint2*>(xs2 + (size_t)row * 512 + col) = make_uint2(h01, h23);
    *reinterpret_cast<uint2*>(xs2 + (size_t)row * 512 + 256 + col) = make_uint2(l01, l23);
}

// ---- dual GEMM, barrier-free K-loop: yl = x@Wl (bf16 out), z = x@(Wr+I)+b ----
// Block: 256 rows x 32 cols, 4 waves (wave = 64 rows x 32 cols, acc 4rt x 2ct x 2out).
// bid = cg*200 + rg  (200 % 8 == 0): all 8 col-group blocks of one row-group map to
// the same XCD (bid%8 == rg%8), so the 256KB A-slab is fetched into that XCD's L2
// once instead of 8x (old mapping put them on 8 different XCDs).
// A: bf16 split pairs from xs2, register-prefetched DEPTH 2 (~600 cyc cover vs
// ~450-500 cyc LLC latency; depth 1 only covered ~300). One barrier total.
__global__ __launch_bounds__(256, 2) void k_gemm4(
    const uint16_t* __restrict__ xs2,
    const uint16_t* __restrict__ whl, const uint16_t* __restrict__ whr,
    const uint16_t* __restrict__ wll, const uint16_t* __restrict__ wlr,
    const float* __restrict__ bias,
    uint16_t* __restrict__ yl, float* __restrict__ outz)
{
    extern __shared__ __align__(16) char smem[];   // 4 mats x 16KB = 64KB
    int bid = blockIdx.x;
    int cg = bid / 200;
    int rg = bid - cg * 200;
    if (rg >= 196) return;
    int t = threadIdx.x;
    int wave = t >> 6, lane = t & 63, quad = lane >> 4, l16 = lane & 15;
    int row0 = rg * 256, col0 = cg * 32;

    // stage B once: LDS[m*16KB + i*4KB + t*16] = W[col0 + i*8 + (t>>5)][((t&31)^(t>>5))*8 ..]
    {
        const uint16_t* mp0 = whl + col0 * 256;
        const uint16_t* mp1 = whr + col0 * 256;
        const uint16_t* mp2 = wll + col0 * 256;
        const uint16_t* mp3 = wlr + col0 * 256;
        int nrow = t >> 5;
        int soff = ((t & 31) ^ nrow) * 8;
#pragma unroll
        for (int i = 0; i < 4; ++i) {
            int go = (i * 8 + nrow) * 256 + soff;
            char* d = smem + i * 4096 + t * 16;
            async_copy16(mp0 + go, d);
            async_copy16(mp1 + go, d + 16384);
            async_copy16(mp2 + go, d + 32768);
            async_copy16(mp3 + go, d + 49152);
        }
    }

    // A fragment pointers (per row-tile); frag = 16B at [row][c*32 + quad*8]
    const uint16_t* ap[4];
#pragma unroll
    for (int rt = 0; rt < 4; ++rt)
        ap[rt] = xs2 + (size_t)(row0 + wave * 64 + rt * 16 + l16) * 512 + quad * 8;

    floatx4 accy[4][2], accz[4][2];
#pragma unroll
    for (int rt = 0; rt < 4; ++rt)
#pragma unroll
        for (int ct = 0; ct < 2; ++ct) {
            accy[rt][ct] = (floatx4){0.f, 0.f, 0.f, 0.f};
            accz[rt][ct] = (floatx4){0.f, 0.f, 0.f, 0.f};
        }

    U8 abuf[3][4];   // depth-2 prefetch ring; all indices unroll-constant
#pragma unroll
    for (int rt = 0; rt < 4; ++rt) {
        abuf[0][rt].v = *reinterpret_cast<const shortx8*>(ap[rt]);
        abuf[1][rt].v = *reinterpret_cast<const shortx8*>(ap[rt] + 32);
    }

    __syncthreads();   // B (and A chunks 0,1) resident; no further barriers

    int bbase0 = l16 * 512;          // ct=0 B-row byte offset
    int bbase1 = (16 + l16) * 512;   // ct=1
    int bxor = l16 & 7;

#pragma unroll
    for (int c = 0; c < 16; ++c) {
        if (c < 14) {
#pragma unroll
            for (int rt = 0; rt < 4; ++rt)
                abuf[(c + 2) % 3][rt].v =
                    *reinterpret_cast<const shortx8*>(ap[rt] + (c + 2) * 32);
        }
        int kk = c & 7;
        int so = ((kk * 4 + quad) ^ bxor) * 16;
        shortx8 b00 = *reinterpret_cast<const shortx8*>(smem + bbase0 + so);           // Wh_l ct0
        shortx8 b10 = *reinterpret_cast<const shortx8*>(smem + bbase1 + so);           // Wh_l ct1
        shortx8 b01 = *reinterpret_cast<const shortx8*>(smem + 16384 + bbase0 + so);   // Wh_r ct0
        shortx8 b11 = *reinterpret_cast<const shortx8*>(smem + 16384 + bbase1 + so);   // Wh_r ct1
        shortx8 c00, c10, c01, c11;
        if (c < 8) {
            c00 = *reinterpret_cast<const shortx8*>(smem + 32768 + bbase0 + so);       // Wlo_l
            c10 = *reinterpret_cast<const shortx8*>(smem + 32768 + bbase1 + so);
            c01 = *reinterpret_cast<const shortx8*>(smem + 49152 + bbase0 + so);       // Wlo_r
            c11 = *reinterpret_cast<const shortx8*>(smem + 49152 + bbase1 + so);
        }
#pragma unroll
        for (int rt = 0; rt < 4; ++rt) {
            shortx8 a = abuf[c % 3][rt].v;
            accy[rt][0] = __builtin_amdgcn_mfma_f32_16x16x32_bf16(a, b00, accy[rt][0], 0, 0, 0);
            accy[rt][1] = __builtin_amdgcn_mfma_f32_16x16x32_bf16(a, b10, accy[rt][1], 0, 0, 0);
            accz[rt][0] = __builtin_amdgcn_mfma_f32_16x16x32_bf16(a, b01, accz[rt][0], 0, 0, 0);
            accz[rt][1] = __builtin_amdgcn_mfma_f32_16x16x32_bf16(a, b11, accz[rt][1], 0, 0, 0);
            if (c < 8) {   // xh pairs with Wlo too; xl (c>=8) pairs with Wh only
                accy[rt][0] = __builtin_amdgcn_mfma_f32_16x16x32_bf16(a, c00, accy[rt][0], 0, 0, 0);
                accy[rt][1] = __builtin_amdgcn_mfma_f32_16x16x32_bf16(a, c10, accy[rt][1], 0, 0, 0);
                accz[rt][0] = __builtin_amdgcn_mfma_f32_16x16x32_bf16(a, c01, accz[rt][0], 0, 0, 0);
                accz[rt][1] = __builtin_amdgcn_mfma_f32_16x16x32_bf16(a, c11, accz[rt][1], 0, 0, 0);
            }
        }
    }

    // epilogue: C/D layout col=l16, row=quad*4+r; bias folded here (z path only)
    float bct[2] = { bias[col0 + l16], bias[col0 + 16 + l16] };
#pragma unroll
    for (int rt = 0; rt < 4; ++rt) {
#pragma unroll
        for (int ct = 0; ct < 2; ++ct) {
            int colg = col0 + ct * 16 + l16;
#pragma unroll
            for (int r = 0; r < 4; ++r) {
                int rowg = row0 + wave * 64 + rt * 16 + quad * 4 + r;
                if (rowg < NN) {
                    yl[(size_t)rowg * 256 + colg] = f2bf(accy[rt][ct][r]);
                    outz[(size_t)rowg * (LL * DD) + colg] = accz[rt][ct][r] + bct[ct];
                }
            }
        }
    }
}

// ---- finish: out = maybe_relu(z + invd*sum yl[nbr]); z already has x-residual
// and bias folded in by the GEMM. Also writes next layer's split input. ----
__global__ __launch_bounds__(256) void k_finish(
    const int* __restrict__ rs, const int* __restrict__ csr,
    const float* __restrict__ invd, const uint16_t* __restrict__ yl,
    uint16_t* __restrict__ xs2, float* __restrict__ outz,
    int do_relu, int wsplit)
{
    int node = blockIdx.x * 4 + (threadIdx.x >> 6);
    int lane = threadIdx.x & 63;
    int col = lane * 4;
    int s = rs[node], e = rs[node + 1];
    float w = invd[node];
    float* zp = outz + (size_t)node * (LL * DD) + col;
    float4 z = *reinterpret_cast<const float4*>(zp);   // hoisted: overlaps the gather
    float a0 = 0.f, a1 = 0.f, a2 = 0.f, a3 = 0.f;
    int p = s;
    // 8-deep gather pipeline (avg degree 16 -> ~2 full iters), then 4/1 tails
    for (; p + 8 <= e; p += 8) {
        int i0 = csr[p],     i1 = csr[p + 1], i2 = csr[p + 2], i3 = csr[p + 3];
        int i4 = csr[p + 4], i5 = csr[p + 5], i6 = csr[p + 6], i7 = csr[p + 7];
        uint2 v0 = *reinterpret_cast<const uint2*>(yl + (size_t)i0 * 256 + col);
        uint2 v1 = *reinterpret_cast<const uint2*>(yl + (size_t)i1 * 256 + col);
        uint2 v2 = *reinterpret_cast<const uint2*>(yl + (size_t)i2 * 256 + col);
        uint2 v3 = *reinterpret_cast<const uint2*>(yl + (size_t)i3 * 256 + col);
        uint2 v4 = *reinterpret_cast<const uint2*>(yl + (size_t)i4 * 256 + col);
        uint2 v5 = *reinterpret_cast<const uint2*>(yl + (size_t)i5 * 256 + col);
        uint2 v6 = *reinterpret_cast<const uint2*>(yl + (size_t)i6 * 256 + col);
        uint2 v7 = *reinterpret_cast<const uint2*>(yl + (size_t)i7 * 256 + col);
        a0 += ((bf2f(v0.x) + bf2f(v1.x)) + (bf2f(v2.x) + bf2f(v3.x)))
            + ((bf2f(v4.x) + bf2f(v5.x)) + (bf2f(v6.x) + bf2f(v7.x)));
        a1 += ((bf2f(v0.x >> 16) + bf2f(v1.x >> 16)) + (bf2f(v2.x >> 16) + bf2f(v3.x >> 16)))
            + ((bf2f(v4.x >> 16) + bf2f(v5.x >> 16)) + (bf2f(v6.x >> 16) + bf2f(v7.x >> 16)));
        a2 += ((bf2f(v0.y) + bf2f(v1.y)) + (bf2f(v2.y) + bf2f(v3.y)))
            + ((bf2f(v4.y) + bf2f(v5.y)) + (bf2f(v6.y) + bf2f(v7.y)));
        a3 += ((bf2f(v0.y >> 16) + bf2f(v1.y >> 16)) + (bf2f(v2.y >> 16) + bf2f(v3.y >> 16)))
            + ((bf2f(v4.y >> 16) + bf2f(v5.y >> 16)) + (bf2f(v6.y >> 16) + bf2f(v7.y >> 16)));
    }
    for (; p + 4 <= e; p += 4) {
        int i0 = csr[p], i1 = csr[p + 1], i2 = csr[p + 2], i3 = csr[p + 3];
        uint2 v0 = *reinterpret_cast<const uint2*>(yl + (size_t)i0 * 256 + col);
        uint2 v1 = *reinterpret_cast<const uint2*>(yl + (size_t)i1 * 256 + col);
        uint2 v2 = *reinterpret_cast<const uint2*>(yl + (size_t)i2 * 256 + col);
        uint2 v3 = *reinterpret_cast<const uint2*>(yl + (size_t)i3 * 256 + col);
        a0 += (bf2f(v0.x) + bf2f(v1.x)) + (bf2f(v2.x) + bf2f(v3.x));
        a1 += (bf2f(v0.x >> 16) + bf2f(v1.x >> 16)) + (bf2f(v2.x >> 16) + bf2f(v3.x >> 16));
        a2 += (bf2f(v0.y) + bf2f(v1.y)) + (bf2f(v2.y) + bf2f(v3.y));
        a3 += (bf2f(v0.y >> 16) + bf2f(v1.y >> 16)) + (bf2f(v2.y >> 16) + bf2f(v3.y >> 16));
    }
    for (; p < e; ++p) {
        int i = csr[p];
        uint2 v = *reinterpret_cast<const uint2*>(yl + (size_t)i * 256 + col);
        a0 += bf2f(v.x); a1 += bf2f(v.x >> 16); a2 += bf2f(v.y); a3 += bf2f(v.y >> 16);
    }
    float o0 = z.x + w * a0;
    float o1 = z.y + w * a1;
    float o2 = z.z + w * a2;
    float o3 = z.w + w * a3;
    if (do_relu) {
        o0 = fmaxf(o0, 0.f); o1 = fmaxf(o1, 0.f);
        o2 = fmaxf(o2, 0.f); o3 = fmaxf(o3, 0.f);
    }
    *reinterpret_cast<float4*>(zp) = make_float4(o0, o1, o2, o3);
    if (wsplit) {   // write next layer's split input
        uint32_t u0 = __float_as_uint(o0), u1 = __float_as_uint(o1);
        uint32_t u2 = __float_as_uint(o2), u3 = __float_as_uint(o3);
        uint32_t h01 = (u0 >> 16) | (u1 & 0xFFFF0000u);
        uint32_t h23 = (u2 >> 16) | (u3 & 0xFFFF0000u);
        uint32_t l01 = (uint32_t)f2bf(o0 - __uint_as_float(u0 & 0xFFFF0000u))
                     | ((uint32_t)f2bf(o1 - __uint_as_float(u1 & 0xFFFF0000u)) << 16);
        uint32_t l23 = (uint32_t)f2bf(o2 - __uint_as_float(u2 & 0xFFFF0000u))
                     | ((uint32_t)f2bf(o3 - __uint_as_float(u3 & 0xFFFF0000u)) << 16);
        *reinterpret_cast<uint2*>(xs2 + (size_t)node * 512 + col) = make_uint2(h01, h23);
        *reinterpret_cast<uint2*>(xs2 + (size_t)node * 512 + 256 + col) = make_uint2(l01, l23);
    }
}

extern "C" void kernel_launch(void* const* d_in, const int* in_sizes, int n_in,
                              void* d_out, int out_size, void* d_ws, size_t ws_size,
                              hipStream_t stream) {
    const int*   edge   = (const int*)d_in[0];     // [2][E]: row0=src, row1=tgt
    const float* x_init = (const float*)d_in[1];   // [N][D] fp32
    const float* W_l    = (const float*)d_in[2];   // [L][D][D] fp32
    const float* W_r    = (const float*)d_in[3];   // [L][D][D] fp32
    const float* bias   = (const float*)d_in[4];   // [L][D] fp32
    float*       out    = (float*)d_out;           // [N][L*D] fp32

    char* ws = (char*)d_ws;
    int*      degI      = (int*)(ws + 0x0000000);
    int*      row_start = (int*)(ws + 0x0040000);
    int*      cursor    = (int*)(ws + 0x0080000);
    float*    invd      = (float*)(ws + 0x00C0000);
    int*      bsum      = (int*)(ws + 0x0100000);
    int*      csr       = (int*)(ws + 0x0140000);        // 3.2 MB
    uint16_t* whl       = (uint16_t*)(ws + 0x0480000);   // 384 KB each (3 layers)
    uint16_t* whr       = (uint16_t*)(ws + 0x04E0000);
    uint16_t* wll       = (uint16_t*)(ws + 0x0540000);
    uint16_t* wlr       = (uint16_t*)(ws + 0x05A0000);
    uint16_t* yl        = (uint16_t*)(ws + 0x0600000);   // NPAD*256*2 = 25.7 MB
    uint16_t* xs2       = (uint16_t*)(ws + 0x1E80000);   // NPAD*512*2 = 51.4 MB (ends ~83 MB)

    hipMemsetAsync(degI, 0, NN * sizeof(int), stream);
    k_count<<<(EE + 255) / 256, 256, 0, stream>>>(edge + EE, degI);
    k_scan1<<<NBLK, 1024, 0, stream>>>(degI, row_start, bsum);
    k_scan2<<<1, 64, 0, stream>>>(bsum, row_start);
    k_init2<<<NBLK, 1024, 0, stream>>>(degI, bsum, row_start, cursor, invd);
    k_scatter<<<(EE + 255) / 256, 256, 0, stream>>>(edge, edge + EE, cursor, csr);
    k_wprep<<<(LL * DD * DD) / 256, 256, 0, stream>>>(W_l, W_r, whl, wll, whr, wlr);
    k_split0<<<NPAD / 4, 256, 0, stream>>>(x_init, xs2);

    for (int i = 0; i < LL; ++i) {
        size_t wo = (size_t)i * DD * DD;
        // grid 1600 = 8 col-groups * 200 (196 row-groups + 4 no-op tail per cg)
        k_gemm4<<<1600, 256, 65536, stream>>>(
            xs2, whl + wo, whr + wo, wll + wo, wlr + wo, bias + (size_t)i * DD,
            yl, out + (size_t)i * DD);
        k_finish<<<NN / 4, 256, 0, stream>>>(
            row_start, csr, invd, yl, xs2,
            out + (size_t)i * DD, (i < LL - 1) ? 1 : 0, (i < LL - 1) ? 1 : 0);
    }
}